// Round 5
// baseline (1446.427 us; speedup 1.0000x reference)
//
#include <hip/hip_runtime.h>
#include <hip/hip_fp16.h>
#include <cmath>

#define Nn   100000
#define Ee   1600000
#define FIN  256
#define Hh   128
#define EDIMM 16
#define NL   3
#define NOUT 64
#define LOG2E 1.4426950408889634f

typedef _Float16 f16x8 __attribute__((ext_vector_type(8)));
typedef float f32x4 __attribute__((ext_vector_type(4)));

static __device__ __forceinline__ __half2 u2h2(unsigned int u) {
  union { unsigned int u; __half2 h; } c; c.u = u; return c.h;
}
static __device__ __forceinline__ unsigned int h22u(__half2 h) {
  union { unsigned int u; __half2 h; } c; c.h = h; return c.u;
}

// v_pk_fma_f16 with op_sel broadcasting lo/hi half of the packed ea operand:
#define PK_FMA_LO(acc, a, w) \
  asm("v_pk_fma_f16 %0, %1, %2, %0 op_sel:[0,0,0] op_sel_hi:[0,1,1]" \
      : "+v"(acc) : "v"(a), "v"(w))
#define PK_FMA_HI(acc, a, w) \
  asm("v_pk_fma_f16 %0, %1, %2, %0 op_sel:[1,0,0] op_sel_hi:[1,1,1]" \
      : "+v"(acc) : "v"(a), "v"(w))

// ---- prep: in_wT[n][k] = in_w[k][n] as fp16 ----
__global__ __launch_bounds__(256) void prep_inw_kernel(const float* __restrict__ in_w,
    __half* __restrict__ in_wT) {
  int i = blockIdx.x * 256 + threadIdx.x;   // 32768 = FIN*Hh
  if (i < FIN * Hh) {
    int k = i >> 7, n = i & 127;
    in_wT[(size_t)n * FIN + k] = __float2half(in_w[i]);
  }
}

// ---- in_proj via MFMA: h = x @ in_w + in_b, K=256 in two phases over shared LDS ----
__global__ __launch_bounds__(256) void in_proj_mfma_kernel(const float* __restrict__ x,
    const __half* __restrict__ in_wT, const float* __restrict__ b, __half* __restrict__ h) {
  __shared__ __half Wl[128][136];
  __shared__ __half Ht[32][136];
  int r0 = blockIdx.x * 32;      // 3125*32 = 100000 exactly
  int tid = threadIdx.x;
  int wv = tid >> 6, lane = tid & 63;
  int rowHalf = wv & 1, colHalf = wv >> 1;
  int quad = lane >> 4, l16 = lane & 15;

  f32x4 acc[4];
#pragma unroll
  for (int t = 0; t < 4; t++) acc[t] = (f32x4){0.f, 0.f, 0.f, 0.f};

  for (int ph = 0; ph < 2; ph++) {
    for (int i = tid; i < 2048; i += 256) {
      int rw = i >> 4, cw = i & 15;
      *(uint4*)(&Wl[rw][cw * 8]) =
          *(const uint4*)(in_wT + (size_t)rw * FIN + ph * 128 + cw * 8);
    }
    for (int i = tid; i < 1024; i += 256) {
      int r = i >> 5, c4 = i & 31;
      float4 f = *(const float4*)(x + (size_t)(r0 + r) * FIN + ph * 128 + c4 * 4);
      *(uint2*)(&Ht[r][c4 * 4]) =
          make_uint2(h22u(__floats2half2_rn(f.x, f.y)), h22u(__floats2half2_rn(f.z, f.w)));
    }
    __syncthreads();
#pragma unroll
    for (int kstep = 0; kstep < 4; kstep++) {
      f16x8 afrag = *(const f16x8*)(&Ht[rowHalf * 16 + l16][kstep * 32 + quad * 8]);
#pragma unroll
      for (int t = 0; t < 4; t++) {
        int n = colHalf * 64 + t * 16 + l16;
        f16x8 bfrag = *(const f16x8*)(&Wl[n][kstep * 32 + quad * 8]);
        acc[t] = __builtin_amdgcn_mfma_f32_16x16x32_f16(afrag, bfrag, acc[t], 0, 0, 0);
      }
    }
    __syncthreads();
  }

#pragma unroll
  for (int t = 0; t < 4; t++) {
    int col = colHalf * 64 + t * 16 + l16;
    float bval = b[col];
#pragma unroll
    for (int r = 0; r < 4; r++) {
      int row = r0 + rowHalf * 16 + quad * 4 + r;
      h[(size_t)row * Hh + col] = __float2half(acc[t][r] + bval);
    }
  }
}

// ---- prep: WtT[l][mat][n][k] = W_mat[l][k][n] as fp16; gate mats (k,q) pre-scaled by log2e ----
__global__ __launch_bounds__(256) void prep_weights_kernel(const float* __restrict__ Wk,
    const float* __restrict__ Wq, const float* __restrict__ Wv, const float* __restrict__ Ws,
    __half* __restrict__ WtT) {
  int mat = blockIdx.x, l = blockIdx.y;
  const float* W = (mat == 0 ? Wk : mat == 1 ? Wq : mat == 2 ? Wv : Ws) + (size_t)l * Hh * Hh;
  float sc = (mat < 2) ? LOG2E : 1.f;
  __half* out = WtT + ((size_t)(l * 4 + mat)) * Hh * Hh;
  for (int i = threadIdx.x; i < Hh * Hh; i += 256) {
    int k = i >> 7, n = i & 127;
    out[(size_t)n * Hh + k] = __float2half(W[i] * sc);
  }
}

// ---- MFMA kqvs FUSED: grid (3125); block computes 32 rows x 128 cols for ALL 4 mats.
// Ht staged once; W(mat+1) prefetched into regs during MFMAs of mat (reg double-buffer).
__global__ __launch_bounds__(256) void kqvs_mfma_kernel(
    const __half* __restrict__ h, const __half* __restrict__ WtT_l,
    const float* __restrict__ bk, const float* __restrict__ bq,
    const float* __restrict__ bv, const float* __restrict__ bs,
    __half* __restrict__ kb, __half* __restrict__ qvj, __half* __restrict__ hnew) {
  __shared__ __half Wl[128][136];
  __shared__ __half Ht[32][136];
  int r0 = blockIdx.x * 32;      // 3125*32 = 100000 exactly
  int tid = threadIdx.x;

  // stage h tile (512 uint4)
  const uint4* hg = (const uint4*)(h + (size_t)r0 * Hh);
  uint4 h0 = hg[tid], h1 = hg[tid + 256];
  // first W into regs
  const uint4* wg0 = (const uint4*)(WtT_l);
  uint4 wreg[8];
#pragma unroll
  for (int j = 0; j < 8; j++) wreg[j] = wg0[tid + 256 * j];
  {
    int rh = tid >> 4, ch = tid & 15;
    *(uint4*)(&Ht[rh][ch * 8]) = h0;
    int i2 = tid + 256;
    rh = i2 >> 4; ch = i2 & 15;
    *(uint4*)(&Ht[rh][ch * 8]) = h1;
  }

  int wv = tid >> 6, lane = tid & 63;
  int rowHalf = wv & 1, colHalf = wv >> 1;
  int quad = lane >> 4, l16 = lane & 15;

#pragma unroll 1
  for (int mat = 0; mat < 4; mat++) {
#pragma unroll
    for (int j = 0; j < 8; j++) {
      int i = tid + 256 * j;
      int rw = i >> 4, cw = i & 15;
      *(uint4*)(&Wl[rw][cw * 8]) = wreg[j];
    }
    __syncthreads();
    if (mat < 3) {   // prefetch next W during this mat's MFMAs
      const uint4* wgn = (const uint4*)(WtT_l + (size_t)(mat + 1) * Hh * Hh);
#pragma unroll
      for (int j = 0; j < 8; j++) wreg[j] = wgn[tid + 256 * j];
    }

    f32x4 acc[4];
#pragma unroll
    for (int t = 0; t < 4; t++) acc[t] = (f32x4){0.f, 0.f, 0.f, 0.f};
#pragma unroll
    for (int kstep = 0; kstep < 4; kstep++) {
      f16x8 afrag = *(const f16x8*)(&Ht[rowHalf * 16 + l16][kstep * 32 + quad * 8]);
#pragma unroll
      for (int t = 0; t < 4; t++) {
        int n = colHalf * 64 + t * 16 + l16;
        f16x8 bfrag = *(const f16x8*)(&Wl[n][kstep * 32 + quad * 8]);
        acc[t] = __builtin_amdgcn_mfma_f32_16x16x32_f16(afrag, bfrag, acc[t], 0, 0, 0);
      }
    }

    const float* bp = (mat == 0) ? bk : (mat == 1) ? bq : (mat == 2) ? bv : bs;
    float bscale = (mat < 2) ? LOG2E : 1.f;
#pragma unroll
    for (int t = 0; t < 4; t++) {
      int col = colHalf * 64 + t * 16 + l16;
      float bval = bp[col] * bscale;
#pragma unroll
      for (int r = 0; r < 4; r++) {
        int row = r0 + rowHalf * 16 + quad * 4 + r;
        __half hv = __float2half(acc[t][r] + bval);
        if (mat == 0)       kb[(size_t)row * Hh + col] = hv;
        else if (mat == 1)  qvj[(size_t)row * 256 + (col >> 1) * 4 + (col & 1)] = hv;
        else if (mat == 2)  qvj[(size_t)row * 256 + (col >> 1) * 4 + 2 + (col & 1)] = hv;
        else                hnew[(size_t)row * Hh + col] = hv;
      }
    }
    __syncthreads();   // all waves done reading Wl before next mat's ds_write
  }
}

// ---------------- CSR build ----------------
__global__ __launch_bounds__(256) void zero_kernel(int* __restrict__ p, int n) {
  int i = blockIdx.x * 256 + threadIdx.x;
  if (i < n) p[i] = 0;
}

__global__ __launch_bounds__(256) void hist_kernel(const int* __restrict__ ei_dst,
                                                   int* __restrict__ counts) {
  int e = blockIdx.x * 256 + threadIdx.x;
  if (e < Ee) atomicAdd(&counts[ei_dst[e]], 1);
}

__global__ __launch_bounds__(256) void scan_block_kernel(const int* __restrict__ counts,
    int* __restrict__ rowptr, int* __restrict__ bsums) {
  __shared__ int tsums[256];
  int b = blockIdx.x, t = threadIdx.x;
  int base = b * 1024 + t * 4;
  int v[4]; int s = 0;
#pragma unroll
  for (int j = 0; j < 4; j++) {
    int idx = base + j;
    v[j] = (idx < Nn) ? counts[idx] : 0;
    s += v[j];
  }
  tsums[t] = s;
  __syncthreads();
  for (int off = 1; off < 256; off <<= 1) {
    int y = (t >= off) ? tsums[t - off] : 0;
    __syncthreads();
    tsums[t] += y;
    __syncthreads();
  }
  int excl = tsums[t] - s;
#pragma unroll
  for (int j = 0; j < 4; j++) {
    int idx = base + j;
    if (idx < Nn) rowptr[idx] = excl;
    excl += v[j];
  }
  if (t == 255) bsums[b] = tsums[255];
}

__global__ __launch_bounds__(128) void scan_sums_kernel(int* __restrict__ bsums, int nb) {
  __shared__ int sh[128];
  int t = threadIdx.x;
  int v = (t < nb) ? bsums[t] : 0;
  sh[t] = v;
  __syncthreads();
  for (int off = 1; off < 128; off <<= 1) {
    int y = (t >= off) ? sh[t - off] : 0;
    __syncthreads();
    sh[t] += y;
    __syncthreads();
  }
  if (t < nb) bsums[t] = sh[t] - v;
}

__global__ __launch_bounds__(256) void finalize_rowptr_kernel(int* __restrict__ rowptr,
    const int* __restrict__ bsums, int* __restrict__ cursor) {
  int i = blockIdx.x * 256 + threadIdx.x;
  if (i < Nn) {
    int r = rowptr[i] + bsums[i >> 10];
    rowptr[i] = r;
    cursor[i] = r;
  }
  if (i == Nn) rowptr[Nn] = Ee;
}

// permute: src_perm (int), ea_perm = raw packed fp16 (8 uints/edge, 32 B)
__global__ __launch_bounds__(256) void fill_perm_kernel(const int* __restrict__ ei_src,
    const int* __restrict__ ei_dst, const float* __restrict__ ea,
    int* __restrict__ cursor, int* __restrict__ src_perm,
    unsigned int* __restrict__ ea_perm) {
  int e = blockIdx.x * 256 + threadIdx.x;
  if (e < Ee) {
    int d = ei_dst[e];
    int slot = atomicAdd(&cursor[d], 1);
    src_perm[slot] = ei_src[e];
    const float4* s = (const float4*)(ea + (size_t)e * EDIMM);
    float4 f0 = s[0], f1 = s[1], f2 = s[2], f3 = s[3];
    uint4* dp = (uint4*)(ea_perm + (size_t)slot * 8);
    dp[0] = make_uint4(h22u(__floats2half2_rn(f0.x, f0.y)), h22u(__floats2half2_rn(f0.z, f0.w)),
                       h22u(__floats2half2_rn(f1.x, f1.y)), h22u(__floats2half2_rn(f1.z, f1.w)));
    dp[1] = make_uint4(h22u(__floats2half2_rn(f2.x, f2.y)), h22u(__floats2half2_rn(f2.z, f2.w)),
                       h22u(__floats2half2_rn(f3.x, f3.y)), h22u(__floats2half2_rn(f3.z, f3.w)));
  }
}

// ---- CSR edge kernel: one wave per FOUR consecutive dst rows ----
// 4 rows/wave: per-wave work ~Poisson(64) -> block tail-wait ~12% vs ~30% at 1 row/wave.
// The 4 rows' CSR segments are contiguous -> ONE ea stage burst + ONE vmcnt drain per 4 rows.
#define EA_CAP4 160   // edges staged per wave (4 rows); 20 KiB/block; overflow path below
__global__ __launch_bounds__(256, 6) void edge_csr_kernel(
    const __half* __restrict__ kb, const __half* __restrict__ qvj,
    const int* __restrict__ src_perm, const unsigned int* __restrict__ ea_perm,
    const int* __restrict__ rowptr,
    const float* __restrict__ We_l, const float* __restrict__ be_l,
    const float* __restrict__ ln_g_l, const float* __restrict__ ln_b_l,
    __half* __restrict__ hbuf) {
  __shared__ uint4 lds_ea[4][EA_CAP4 * 2];   // 4 waves x 160 edges x 32 B = 20 KiB
  int wave = threadIdx.x >> 6;
  int lane = threadIdx.x & 63;
  int r0 = (blockIdx.x * 4 + wave) * 4;   // grid 6250*4 waves*4 rows = 100000 exactly
  int c0 = lane * 2;

  unsigned wpk[EDIMM];   // We columns (c0,c0+1) per dim, fp16 pair, pre-scaled by log2e
#pragma unroll
  for (int d = 0; d < EDIMM; d++) {
    float2 wv = *(const float2*)(We_l + d * Hh + c0);
    wpk[d] = h22u(__floats2half2_rn(wv.x * LOG2E, wv.y * LOG2E));
  }
  float2 bef = *(const float2*)(be_l + c0);
  __half2 bev = __floats2half2_rn(bef.x * LOG2E, bef.y * LOG2E);

  int4 rp4 = *(const int4*)(rowptr + r0);
  int rp[5] = {rp4.x, rp4.y, rp4.z, rp4.w, rowptr[r0 + 4]};

  unsigned kbev_u[4];
#pragma unroll
  for (int ri = 0; ri < 4; ri++)
    kbev_u[ri] = h22u(__hadd2(*(const __half2*)(kb + (size_t)(r0 + ri) * Hh + c0), bev));

  int nl = rp[4] - rp[0];
  if (nl > EA_CAP4) nl = EA_CAP4;   // edges resident in LDS (local idx < nl)

  // ---- stage all 4 rows' ea (contiguous in CSR order) into LDS ----
  char* lbase = (char*)&lds_ea[wave][0];
  {
    int row_bytes = nl << 5;
    const char* gsrc = (const char*)(ea_perm + (size_t)rp[0] * 8);
    for (int c = 0; c < row_bytes; c += 1024) {
      int o = c + lane * 16;
      if (o < row_bytes) {
        __builtin_amdgcn_global_load_lds(
            (__attribute__((address_space(1))) void*)(gsrc + o),
            (__attribute__((address_space(3))) void*)(lbase + c),
            16, 0, 0);
      }
    }
  }

  const char* qvb = (const char*)qvj;
  unsigned loff = (unsigned)(lane << 3);
  const int* spb = src_perm + rp[0];   // local-index base

#pragma unroll
  for (int ri = 0; ri < 4; ri++) {
    unsigned kb_u = kbev_u[ri];
    float agg0 = 0.f, agg1 = 0.f;
    int ls = rp[ri] - rp[0];
    int le = rp[ri + 1] - rp[0];
    int lend = le < nl ? le : nl;
    if (lend < ls) lend = ls;

    auto edge_math = [&](uint4 eA, uint4 eB, uint2 qv) {
      unsigned acc = kb_u;
      PK_FMA_LO(acc, eA.x, wpk[0]);  PK_FMA_HI(acc, eA.x, wpk[1]);
      PK_FMA_LO(acc, eA.y, wpk[2]);  PK_FMA_HI(acc, eA.y, wpk[3]);
      PK_FMA_LO(acc, eA.z, wpk[4]);  PK_FMA_HI(acc, eA.z, wpk[5]);
      PK_FMA_LO(acc, eA.w, wpk[6]);  PK_FMA_HI(acc, eA.w, wpk[7]);
      PK_FMA_LO(acc, eB.x, wpk[8]);  PK_FMA_HI(acc, eB.x, wpk[9]);
      PK_FMA_LO(acc, eB.y, wpk[10]); PK_FMA_HI(acc, eB.y, wpk[11]);
      PK_FMA_LO(acc, eB.z, wpk[12]); PK_FMA_HI(acc, eB.z, wpk[13]);
      PK_FMA_LO(acc, eB.w, wpk[14]); PK_FMA_HI(acc, eB.w, wpk[15]);
      __half2 pre = __hadd2(u2h2(acc), u2h2(qv.x));
      float p0 = __half2float(__low2half(pre));
      float p1 = __half2float(__high2half(pre));
      float ex0, ex1;
      asm("v_exp_f32 %0, -%1" : "=v"(ex0) : "v"(p0));   // exp2(-pre); pre is log2e-scaled
      asm("v_exp_f32 %0, -%1" : "=v"(ex1) : "v"(p1));
      float g0 = __builtin_amdgcn_rcpf(1.f + ex0);
      float g1 = __builtin_amdgcn_rcpf(1.f + ex1);
      __half2 vh = u2h2(qv.y);
      agg0 += g0 * __half2float(__low2half(vh));
      agg1 += g1 * __half2float(__high2half(vh));
    };

    int e = ls;
    int nfull = (lend - e) & ~3;
    int nfe = e + nfull;
    uint2 qA0, qA1, qA2, qA3;
    if (nfull) {
      int4 s4 = *(const int4*)(spb + e);
      qA0 = *(const uint2*)(qvb + (((unsigned)s4.x << 9) + loff));
      qA1 = *(const uint2*)(qvb + (((unsigned)s4.y << 9) + loff));
      qA2 = *(const uint2*)(qvb + (((unsigned)s4.z << 9) + loff));
      qA3 = *(const uint2*)(qvb + (((unsigned)s4.w << 9) + loff));
    }
    // ri=0: drains ea staging + first gathers. ri>0: drains only the 4 fresh gathers.
    asm volatile("s_waitcnt vmcnt(0)" ::: "memory");

    for (; e + 8 <= nfe; e += 4) {
      int4 s4n = *(const int4*)(spb + e + 4);
      uint2 qB0 = *(const uint2*)(qvb + (((unsigned)s4n.x << 9) + loff));
      uint2 qB1 = *(const uint2*)(qvb + (((unsigned)s4n.y << 9) + loff));
      uint2 qB2 = *(const uint2*)(qvb + (((unsigned)s4n.z << 9) + loff));
      uint2 qB3 = *(const uint2*)(qvb + (((unsigned)s4n.w << 9) + loff));
      const uint4* ee = (const uint4*)(lbase + (e << 5));
      edge_math(ee[0], ee[1], qA0);
      edge_math(ee[2], ee[3], qA1);
      edge_math(ee[4], ee[5], qA2);
      edge_math(ee[6], ee[7], qA3);
      qA0 = qB0; qA1 = qB1; qA2 = qB2; qA3 = qB3;
    }
    if (nfull) {
      const uint4* ee = (const uint4*)(lbase + (e << 5));
      edge_math(ee[0], ee[1], qA0);
      edge_math(ee[2], ee[3], qA1);
      edge_math(ee[4], ee[5], qA2);
      edge_math(ee[6], ee[7], qA3);
      e += 4;
    }
    for (; e < lend; e++) {
      int src = spb[e];
      uint2 qv = *(const uint2*)(qvb + (((unsigned)src << 9) + loff));
      const uint4* ee = (const uint4*)(lbase + (e << 5));
      edge_math(ee[0], ee[1], qv);
    }
    // overflow beyond EA_CAP4 (statistically never for Poisson(64); kept for safety)
    for (int eg = rp[0] + lend; eg < rp[ri + 1]; eg++) {
      int src = src_perm[eg];
      const uint4* eb = (const uint4*)(ea_perm + (size_t)eg * 8);
      uint4 a0 = eb[0], a1 = eb[1];
      uint2 qv = *(const uint2*)(qvb + (((unsigned)src << 9) + loff));
      edge_math(a0, a1, qv);
    }

    // skip + LayerNorm + GELU (wave owns full row: 2 channels/lane)
    int row = r0 + ri;
    __half2 hv2 = *(const __half2*)(hbuf + (size_t)row * Hh + c0);
    float y0 = __half2float(hv2.x) + agg0, y1 = __half2float(hv2.y) + agg1;
    float s = y0 + y1;
#pragma unroll
    for (int off = 32; off; off >>= 1) s += __shfl_xor(s, off);
    float mu = s * (1.f / 128.f);
    float d0 = y0 - mu, d1 = y1 - mu;
    float vv = d0 * d0 + d1 * d1;
#pragma unroll
    for (int off = 32; off; off >>= 1) vv += __shfl_xor(vv, off);
    float rstd = rsqrtf(vv * (1.f / 128.f) + 1e-5f);
    float2 lg = *(const float2*)(ln_g_l + c0);
    float2 lb = *(const float2*)(ln_b_l + c0);
    float o0 = d0 * rstd * lg.x + lb.x;
    float o1 = d1 * rstd * lg.y + lb.y;
    o0 = 0.5f * o0 * (1.f + erff(o0 * 0.70710678118654752f));
    o1 = 0.5f * o1 * (1.f + erff(o1 * 0.70710678118654752f));
    *(__half2*)(hbuf + (size_t)row * Hh + c0) = __floats2half2_rn(o0, o1);
  }
}

// ---- out_proj: out = h @ out_w  [N,128]@[128,64], h fp16 ----
__global__ __launch_bounds__(64) void out_proj_kernel(const __half* __restrict__ h,
    const float* __restrict__ w, float* __restrict__ out) {
  __shared__ float hs[16][Hh];
  int r0 = blockIdx.x * 16;    // 6250*16 = 100000 exactly
  const uint4* hg = (const uint4*)(h + (size_t)r0 * Hh);
  for (int i = threadIdx.x; i < 256; i += 64) {
    uint4 u = hg[i];
    int r = i >> 4, c = (i & 15) * 8;
    __half2 ha = u2h2(u.x), hb = u2h2(u.y), hc = u2h2(u.z), hd = u2h2(u.w);
    hs[r][c+0] = __half2float(ha.x); hs[r][c+1] = __half2float(ha.y);
    hs[r][c+2] = __half2float(hb.x); hs[r][c+3] = __half2float(hb.y);
    hs[r][c+4] = __half2float(hc.x); hs[r][c+5] = __half2float(hc.y);
    hs[r][c+6] = __half2float(hd.x); hs[r][c+7] = __half2float(hd.y);
  }
  __syncthreads();
  int t = threadIdx.x;
  float acc[16] = {};
  for (int kk = 0; kk < Hh; kk++) {
    float wv = w[kk * NOUT + t];
#pragma unroll
    for (int r = 0; r < 16; r++) acc[r] += hs[r][kk] * wv;
  }
#pragma unroll
  for (int r = 0; r < 16; r++) out[(size_t)(r0 + r) * NOUT + t] = acc[r];
}

extern "C" void kernel_launch(void* const* d_in, const int* in_sizes, int n_in,
                              void* d_out, int out_size, void* d_ws, size_t ws_size,
                              hipStream_t stream) {
  const float* x    = (const float*)d_in[0];
  const int*   ei   = (const int*)d_in[1];
  const float* ea   = (const float*)d_in[2];
  const float* in_w = (const float*)d_in[3];
  const float* in_b = (const float*)d_in[4];
  const float* Wk   = (const float*)d_in[5];
  const float* bk   = (const float*)d_in[6];
  const float* Wq   = (const float*)d_in[7];
  const float* bq   = (const float*)d_in[8];
  const float* Wv   = (const float*)d_in[9];
  const float* bv   = (const float*)d_in[10];
  const float* We   = (const float*)d_in[11];
  const float* be   = (const float*)d_in[12];
  const float* Ws   = (const float*)d_in[13];
  const float* bs   = (const float*)d_in[14];
  const float* ln_g = (const float*)d_in[15];
  const float* ln_b = (const float*)d_in[16];
  const float* out_w = (const float*)d_in[17];
  float* out = (float*)d_out;

  const int* ei_src = ei;
  const int* ei_dst = ei + Ee;

  size_t NH = (size_t)Nn * Hh;
  char* wsp = (char*)d_ws;
  __half* hA = (__half*)wsp;          wsp += NH * 2;
  __half* hB = (__half*)wsp;          wsp += NH * 2;
  __half* kb = (__half*)wsp;          wsp += NH * 2;
  __half* qvj = (__half*)wsp;         wsp += NH * 2 * 2;   // [N,256] pair-interleaved q|v
  __half* WtT = (__half*)wsp;         wsp += (size_t)NL * 4 * Hh * Hh * 2;
  __half* in_wT = (__half*)wsp;       wsp += (size_t)FIN * Hh * 2;
  int* rowptr = (int*)wsp;            wsp += (Nn + 1) * 4;
  int* cursor = (int*)wsp;            wsp += Nn * 4;
  int* bsums  = (int*)wsp;            wsp += 128 * 4;
  int* src_perm = (int*)wsp;          wsp += (size_t)Ee * 4;
  unsigned int* ea_perm = (unsigned int*)wsp; wsp += (size_t)Ee * 32;

  const int NB_SCAN = (Nn + 1023) / 1024;   // 98

  zero_kernel<<<(Nn + 255) / 256, 256, 0, stream>>>(cursor, Nn);
  hist_kernel<<<(Ee + 255) / 256, 256, 0, stream>>>(ei_dst, cursor);
  scan_block_kernel<<<NB_SCAN, 256, 0, stream>>>(cursor, rowptr, bsums);
  scan_sums_kernel<<<1, 128, 0, stream>>>(bsums, NB_SCAN);
  finalize_rowptr_kernel<<<(Nn + 1 + 255) / 256, 256, 0, stream>>>(rowptr, bsums, cursor);
  fill_perm_kernel<<<(Ee + 255) / 256, 256, 0, stream>>>(ei_src, ei_dst, ea, cursor,
                                                         src_perm, ea_perm);
  prep_weights_kernel<<<dim3(4, NL), 256, 0, stream>>>(Wk, Wq, Wv, Ws, WtT);
  prep_inw_kernel<<<(FIN * Hh + 255) / 256, 256, 0, stream>>>(in_w, in_wT);

  in_proj_mfma_kernel<<<Nn / 32, 256, 0, stream>>>(x, in_wT, in_b, hA);

  __half* h  = hA;
  __half* hn = hB;
  for (int l = 0; l < NL; l++) {
    kqvs_mfma_kernel<<<Nn / 32, 256, 0, stream>>>(h,
        WtT + (size_t)l * 4 * Hh * Hh,
        bk + l * Hh, bq + l * Hh, bv + l * Hh, bs + l * Hh,
        kb, qvj, hn);
    edge_csr_kernel<<<Nn / 16, 256, 0, stream>>>(kb, qvj, src_perm, ea_perm,
        rowptr, We + l * EDIMM * Hh, be + l * Hh,
        ln_g + l * Hh, ln_b + l * Hh, hn);
    __half* tmp = h; h = hn; hn = tmp;
  }

  out_proj_kernel<<<Nn / 16, 64, 0, stream>>>(h, out_w, out);
}

// Round 6
// 1184.576 us; speedup vs baseline: 1.2211x; 1.2211x over previous
//
#include <hip/hip_runtime.h>
#include <hip/hip_fp16.h>
#include <cmath>

#define Nn   100000
#define Ee   1600000
#define FIN  256
#define Hh   128
#define EDIMM 16
#define NL   3
#define NOUT 64
#define LOG2E 1.4426950408889634f

typedef _Float16 f16x8 __attribute__((ext_vector_type(8)));
typedef float f32x4 __attribute__((ext_vector_type(4)));

static __device__ __forceinline__ __half2 u2h2(unsigned int u) {
  union { unsigned int u; __half2 h; } c; c.u = u; return c.h;
}
static __device__ __forceinline__ unsigned int h22u(__half2 h) {
  union { unsigned int u; __half2 h; } c; c.h = h; return c.u;
}

// v_pk_fma_f16 with op_sel broadcasting lo/hi half of the packed ea operand:
#define PK_FMA_LO(acc, a, w) \
  asm("v_pk_fma_f16 %0, %1, %2, %0 op_sel:[0,0,0] op_sel_hi:[0,1,1]" \
      : "+v"(acc) : "v"(a), "v"(w))
#define PK_FMA_HI(acc, a, w) \
  asm("v_pk_fma_f16 %0, %1, %2, %0 op_sel:[1,0,0] op_sel_hi:[1,1,1]" \
      : "+v"(acc) : "v"(a), "v"(w))

// ---- prep: in_wT[n][k] = in_w[k][n] as fp16 ----
__global__ __launch_bounds__(256) void prep_inw_kernel(const float* __restrict__ in_w,
    __half* __restrict__ in_wT) {
  int i = blockIdx.x * 256 + threadIdx.x;   // 32768 = FIN*Hh
  if (i < FIN * Hh) {
    int k = i >> 7, n = i & 127;
    in_wT[(size_t)n * FIN + k] = __float2half(in_w[i]);
  }
}

// ---- in_proj via MFMA: h = x @ in_w + in_b, K=256 in two phases over shared LDS ----
__global__ __launch_bounds__(256) void in_proj_mfma_kernel(const float* __restrict__ x,
    const __half* __restrict__ in_wT, const float* __restrict__ b, __half* __restrict__ h) {
  __shared__ __half Wl[128][136];
  __shared__ __half Ht[32][136];
  int r0 = blockIdx.x * 32;      // 3125*32 = 100000 exactly
  int tid = threadIdx.x;
  int wv = tid >> 6, lane = tid & 63;
  int rowHalf = wv & 1, colHalf = wv >> 1;
  int quad = lane >> 4, l16 = lane & 15;

  f32x4 acc[4];
#pragma unroll
  for (int t = 0; t < 4; t++) acc[t] = (f32x4){0.f, 0.f, 0.f, 0.f};

  for (int ph = 0; ph < 2; ph++) {
    for (int i = tid; i < 2048; i += 256) {
      int rw = i >> 4, cw = i & 15;
      *(uint4*)(&Wl[rw][cw * 8]) =
          *(const uint4*)(in_wT + (size_t)rw * FIN + ph * 128 + cw * 8);
    }
    for (int i = tid; i < 1024; i += 256) {
      int r = i >> 5, c4 = i & 31;
      float4 f = *(const float4*)(x + (size_t)(r0 + r) * FIN + ph * 128 + c4 * 4);
      *(uint2*)(&Ht[r][c4 * 4]) =
          make_uint2(h22u(__floats2half2_rn(f.x, f.y)), h22u(__floats2half2_rn(f.z, f.w)));
    }
    __syncthreads();
#pragma unroll
    for (int kstep = 0; kstep < 4; kstep++) {
      f16x8 afrag = *(const f16x8*)(&Ht[rowHalf * 16 + l16][kstep * 32 + quad * 8]);
#pragma unroll
      for (int t = 0; t < 4; t++) {
        int n = colHalf * 64 + t * 16 + l16;
        f16x8 bfrag = *(const f16x8*)(&Wl[n][kstep * 32 + quad * 8]);
        acc[t] = __builtin_amdgcn_mfma_f32_16x16x32_f16(afrag, bfrag, acc[t], 0, 0, 0);
      }
    }
    __syncthreads();
  }

#pragma unroll
  for (int t = 0; t < 4; t++) {
    int col = colHalf * 64 + t * 16 + l16;
    float bval = b[col];
#pragma unroll
    for (int r = 0; r < 4; r++) {
      int row = r0 + rowHalf * 16 + quad * 4 + r;
      h[(size_t)row * Hh + col] = __float2half(acc[t][r] + bval);
    }
  }
}

// ---- prep: WtT[l][mat][n][k] = W_mat[l][k][n] as fp16; gate mats (k,q) pre-scaled by log2e ----
__global__ __launch_bounds__(256) void prep_weights_kernel(const float* __restrict__ Wk,
    const float* __restrict__ Wq, const float* __restrict__ Wv, const float* __restrict__ Ws,
    __half* __restrict__ WtT) {
  int mat = blockIdx.x, l = blockIdx.y;
  const float* W = (mat == 0 ? Wk : mat == 1 ? Wq : mat == 2 ? Wv : Ws) + (size_t)l * Hh * Hh;
  float sc = (mat < 2) ? LOG2E : 1.f;
  __half* out = WtT + ((size_t)(l * 4 + mat)) * Hh * Hh;
  for (int i = threadIdx.x; i < Hh * Hh; i += 256) {
    int k = i >> 7, n = i & 127;
    out[(size_t)n * Hh + k] = __float2half(W[i] * sc);
  }
}

// ---- MFMA kqvs: grid (4, 3125); block computes 32 rows x 128 cols of one matrix ----
// (reverted to the 4-block version: R5's fused variant regressed ~200 us)
__global__ __launch_bounds__(256) void kqvs_mfma_kernel(
    const __half* __restrict__ h, const __half* __restrict__ WtT_l,
    const float* __restrict__ bk, const float* __restrict__ bq,
    const float* __restrict__ bv, const float* __restrict__ bs,
    __half* __restrict__ kb, __half* __restrict__ qvj, __half* __restrict__ hnew) {
  __shared__ __half Wl[128][136];
  __shared__ __half Ht[32][136];
  int mat = blockIdx.x;
  int r0 = blockIdx.y * 32;      // 3125*32 = 100000 exactly
  int tid = threadIdx.x;

  const uint4* wg = (const uint4*)(WtT_l + (size_t)mat * Hh * Hh);
  for (int i = tid; i < 2048; i += 256) {
    int rw = i >> 4, cw = i & 15;
    *(uint4*)(&Wl[rw][cw * 8]) = wg[i];
  }
  const uint4* hg = (const uint4*)(h + (size_t)r0 * Hh);
  for (int i = tid; i < 512; i += 256) {
    int rh = i >> 4, ch = i & 15;
    *(uint4*)(&Ht[rh][ch * 8]) = hg[i];
  }
  __syncthreads();

  int wv = tid >> 6, lane = tid & 63;
  int rowHalf = wv & 1, colHalf = wv >> 1;
  int quad = lane >> 4, l16 = lane & 15;

  f32x4 acc[4];
#pragma unroll
  for (int t = 0; t < 4; t++) acc[t] = (f32x4){0.f, 0.f, 0.f, 0.f};

#pragma unroll
  for (int kstep = 0; kstep < 4; kstep++) {
    f16x8 afrag = *(const f16x8*)(&Ht[rowHalf * 16 + l16][kstep * 32 + quad * 8]);
#pragma unroll
    for (int t = 0; t < 4; t++) {
      int n = colHalf * 64 + t * 16 + l16;
      f16x8 bfrag = *(const f16x8*)(&Wl[n][kstep * 32 + quad * 8]);
      acc[t] = __builtin_amdgcn_mfma_f32_16x16x32_f16(afrag, bfrag, acc[t], 0, 0, 0);
    }
  }

  const float* bp = (mat == 0) ? bk : (mat == 1) ? bq : (mat == 2) ? bv : bs;
  float bscale = (mat < 2) ? LOG2E : 1.f;
#pragma unroll
  for (int t = 0; t < 4; t++) {
    int col = colHalf * 64 + t * 16 + l16;
    float bval = bp[col] * bscale;
#pragma unroll
    for (int r = 0; r < 4; r++) {
      int row = r0 + rowHalf * 16 + quad * 4 + r;
      __half hv = __float2half(acc[t][r] + bval);
      if (mat == 0)       kb[(size_t)row * Hh + col] = hv;
      else if (mat == 1)  qvj[(size_t)row * 256 + (col >> 1) * 4 + (col & 1)] = hv;
      else if (mat == 2)  qvj[(size_t)row * 256 + (col >> 1) * 4 + 2 + (col & 1)] = hv;
      else                hnew[(size_t)row * Hh + col] = hv;
    }
  }
}

// ---------------- CSR build ----------------
__global__ __launch_bounds__(256) void zero_kernel(int* __restrict__ p, int n) {
  int i = blockIdx.x * 256 + threadIdx.x;
  if (i < n) p[i] = 0;
}

__global__ __launch_bounds__(256) void hist_kernel(const int* __restrict__ ei_dst,
                                                   int* __restrict__ counts) {
  int e = blockIdx.x * 256 + threadIdx.x;
  if (e < Ee) atomicAdd(&counts[ei_dst[e]], 1);
}

__global__ __launch_bounds__(256) void scan_block_kernel(const int* __restrict__ counts,
    int* __restrict__ rowptr, int* __restrict__ bsums) {
  __shared__ int tsums[256];
  int b = blockIdx.x, t = threadIdx.x;
  int base = b * 1024 + t * 4;
  int v[4]; int s = 0;
#pragma unroll
  for (int j = 0; j < 4; j++) {
    int idx = base + j;
    v[j] = (idx < Nn) ? counts[idx] : 0;
    s += v[j];
  }
  tsums[t] = s;
  __syncthreads();
  for (int off = 1; off < 256; off <<= 1) {
    int y = (t >= off) ? tsums[t - off] : 0;
    __syncthreads();
    tsums[t] += y;
    __syncthreads();
  }
  int excl = tsums[t] - s;
#pragma unroll
  for (int j = 0; j < 4; j++) {
    int idx = base + j;
    if (idx < Nn) rowptr[idx] = excl;
    excl += v[j];
  }
  if (t == 255) bsums[b] = tsums[255];
}

__global__ __launch_bounds__(128) void scan_sums_kernel(int* __restrict__ bsums, int nb) {
  __shared__ int sh[128];
  int t = threadIdx.x;
  int v = (t < nb) ? bsums[t] : 0;
  sh[t] = v;
  __syncthreads();
  for (int off = 1; off < 128; off <<= 1) {
    int y = (t >= off) ? sh[t - off] : 0;
    __syncthreads();
    sh[t] += y;
    __syncthreads();
  }
  if (t < nb) bsums[t] = sh[t] - v;
}

__global__ __launch_bounds__(256) void finalize_rowptr_kernel(int* __restrict__ rowptr,
    const int* __restrict__ bsums, int* __restrict__ cursor) {
  int i = blockIdx.x * 256 + threadIdx.x;
  if (i < Nn) {
    int r = rowptr[i] + bsums[i >> 10];
    rowptr[i] = r;
    cursor[i] = r;
  }
  if (i == Nn) rowptr[Nn] = Ee;
}

// permute: src_perm (int), ea_perm = raw packed fp16 (8 uints/edge, 32 B)
__global__ __launch_bounds__(256) void fill_perm_kernel(const int* __restrict__ ei_src,
    const int* __restrict__ ei_dst, const float* __restrict__ ea,
    int* __restrict__ cursor, int* __restrict__ src_perm,
    unsigned int* __restrict__ ea_perm) {
  int e = blockIdx.x * 256 + threadIdx.x;
  if (e < Ee) {
    int d = ei_dst[e];
    int slot = atomicAdd(&cursor[d], 1);
    src_perm[slot] = ei_src[e];
    const float4* s = (const float4*)(ea + (size_t)e * EDIMM);
    float4 f0 = s[0], f1 = s[1], f2 = s[2], f3 = s[3];
    uint4* dp = (uint4*)(ea_perm + (size_t)slot * 8);
    dp[0] = make_uint4(h22u(__floats2half2_rn(f0.x, f0.y)), h22u(__floats2half2_rn(f0.z, f0.w)),
                       h22u(__floats2half2_rn(f1.x, f1.y)), h22u(__floats2half2_rn(f1.z, f1.w)));
    dp[1] = make_uint4(h22u(__floats2half2_rn(f2.x, f2.y)), h22u(__floats2half2_rn(f2.z, f2.w)),
                       h22u(__floats2half2_rn(f3.x, f3.y)), h22u(__floats2half2_rn(f3.z, f3.w)));
  }
}

// ---- CSR edge kernel: one wave per TWO consecutive dst rows ----
// 2 rows/wave, register-tight (+4 scalars vs 1-row; R5's 4-row variant spilled).
// Per-wave work ~Poisson(32): block tail-wait ~16% vs ~31% at 1 row/wave.
// The 2 rows' CSR segments are contiguous -> ONE ea stage burst per 2 rows.
#define EA_CAP2 80   // edges staged per wave (2 rows); 10 KiB/block; overflow path below
__global__ __launch_bounds__(256, 6) void edge_csr_kernel(
    const __half* __restrict__ kb, const __half* __restrict__ qvj,
    const int* __restrict__ src_perm, const unsigned int* __restrict__ ea_perm,
    const int* __restrict__ rowptr,
    const float* __restrict__ We_l, const float* __restrict__ be_l,
    const float* __restrict__ ln_g_l, const float* __restrict__ ln_b_l,
    __half* __restrict__ hbuf) {
  __shared__ uint4 lds_ea[4][EA_CAP2 * 2];   // 4 waves x 80 edges x 32 B = 10 KiB
  int wave = threadIdx.x >> 6;
  int lane = threadIdx.x & 63;
  int r0 = (blockIdx.x * 4 + wave) * 2;   // grid 12500*4 waves*2 rows = 100000 exactly
  int c0 = lane * 2;

  unsigned wpk[EDIMM];   // We columns (c0,c0+1) per dim, fp16 pair, pre-scaled by log2e
#pragma unroll
  for (int d = 0; d < EDIMM; d++) {
    float2 wv = *(const float2*)(We_l + d * Hh + c0);
    wpk[d] = h22u(__floats2half2_rn(wv.x * LOG2E, wv.y * LOG2E));
  }
  float2 bef = *(const float2*)(be_l + c0);
  __half2 bev = __floats2half2_rn(bef.x * LOG2E, bef.y * LOG2E);

  int rpA = rowptr[r0], rpB = rowptr[r0 + 1], rpC = rowptr[r0 + 2];

  unsigned kbev0 = h22u(__hadd2(*(const __half2*)(kb + (size_t)r0 * Hh + c0), bev));
  unsigned kbev1 = h22u(__hadd2(*(const __half2*)(kb + (size_t)(r0 + 1) * Hh + c0), bev));

  int nl = rpC - rpA;
  if (nl > EA_CAP2) nl = EA_CAP2;   // edges resident in LDS (local idx < nl)

  // ---- stage both rows' ea (contiguous in CSR order) into LDS ----
  char* lbase = (char*)&lds_ea[wave][0];
  {
    int row_bytes = nl << 5;
    const char* gsrc = (const char*)(ea_perm + (size_t)rpA * 8);
    for (int c = 0; c < row_bytes; c += 1024) {
      int o = c + lane * 16;
      if (o < row_bytes) {
        __builtin_amdgcn_global_load_lds(
            (__attribute__((address_space(1))) void*)(gsrc + o),
            (__attribute__((address_space(3))) void*)(lbase + c),
            16, 0, 0);
      }
    }
  }

  const char* qvb = (const char*)qvj;
  unsigned loff = (unsigned)(lane << 3);
  const int* spb = src_perm + rpA;   // local-index base

#pragma unroll
  for (int ri = 0; ri < 2; ri++) {
    unsigned kb_u = ri ? kbev1 : kbev0;
    float agg0 = 0.f, agg1 = 0.f;
    int ls = (ri ? rpB : rpA) - rpA;
    int le = (ri ? rpC : rpB) - rpA;
    int lend = le < nl ? le : nl;
    if (lend < ls) lend = ls;

    auto edge_math = [&](uint4 eA, uint4 eB, uint2 qv) {
      unsigned acc = kb_u;
      PK_FMA_LO(acc, eA.x, wpk[0]);  PK_FMA_HI(acc, eA.x, wpk[1]);
      PK_FMA_LO(acc, eA.y, wpk[2]);  PK_FMA_HI(acc, eA.y, wpk[3]);
      PK_FMA_LO(acc, eA.z, wpk[4]);  PK_FMA_HI(acc, eA.z, wpk[5]);
      PK_FMA_LO(acc, eA.w, wpk[6]);  PK_FMA_HI(acc, eA.w, wpk[7]);
      PK_FMA_LO(acc, eB.x, wpk[8]);  PK_FMA_HI(acc, eB.x, wpk[9]);
      PK_FMA_LO(acc, eB.y, wpk[10]); PK_FMA_HI(acc, eB.y, wpk[11]);
      PK_FMA_LO(acc, eB.z, wpk[12]); PK_FMA_HI(acc, eB.z, wpk[13]);
      PK_FMA_LO(acc, eB.w, wpk[14]); PK_FMA_HI(acc, eB.w, wpk[15]);
      __half2 pre = __hadd2(u2h2(acc), u2h2(qv.x));
      float p0 = __half2float(__low2half(pre));
      float p1 = __half2float(__high2half(pre));
      float ex0, ex1;
      asm("v_exp_f32 %0, -%1" : "=v"(ex0) : "v"(p0));   // exp2(-pre); pre is log2e-scaled
      asm("v_exp_f32 %0, -%1" : "=v"(ex1) : "v"(p1));
      float g0 = __builtin_amdgcn_rcpf(1.f + ex0);
      float g1 = __builtin_amdgcn_rcpf(1.f + ex1);
      __half2 vh = u2h2(qv.y);
      agg0 += g0 * __half2float(__low2half(vh));
      agg1 += g1 * __half2float(__high2half(vh));
    };

    int e = ls;
    int nfull = (lend - e) & ~3;
    int nfe = e + nfull;
    uint2 qA0, qA1, qA2, qA3;
    if (nfull) {
      int4 s4 = *(const int4*)(spb + e);
      qA0 = *(const uint2*)(qvb + (((unsigned)s4.x << 9) + loff));
      qA1 = *(const uint2*)(qvb + (((unsigned)s4.y << 9) + loff));
      qA2 = *(const uint2*)(qvb + (((unsigned)s4.z << 9) + loff));
      qA3 = *(const uint2*)(qvb + (((unsigned)s4.w << 9) + loff));
    }
    // ri=0: drains ea staging + first gathers. ri=1: drains only its fresh gathers.
    asm volatile("s_waitcnt vmcnt(0)" ::: "memory");

    for (; e + 8 <= nfe; e += 4) {
      int4 s4n = *(const int4*)(spb + e + 4);
      uint2 qB0 = *(const uint2*)(qvb + (((unsigned)s4n.x << 9) + loff));
      uint2 qB1 = *(const uint2*)(qvb + (((unsigned)s4n.y << 9) + loff));
      uint2 qB2 = *(const uint2*)(qvb + (((unsigned)s4n.z << 9) + loff));
      uint2 qB3 = *(const uint2*)(qvb + (((unsigned)s4n.w << 9) + loff));
      const uint4* ee = (const uint4*)(lbase + (e << 5));
      edge_math(ee[0], ee[1], qA0);
      edge_math(ee[2], ee[3], qA1);
      edge_math(ee[4], ee[5], qA2);
      edge_math(ee[6], ee[7], qA3);
      qA0 = qB0; qA1 = qB1; qA2 = qB2; qA3 = qB3;
    }
    if (nfull) {
      const uint4* ee = (const uint4*)(lbase + (e << 5));
      edge_math(ee[0], ee[1], qA0);
      edge_math(ee[2], ee[3], qA1);
      edge_math(ee[4], ee[5], qA2);
      edge_math(ee[6], ee[7], qA3);
      e += 4;
    }
    for (; e < lend; e++) {
      int src = spb[e];
      uint2 qv = *(const uint2*)(qvb + (((unsigned)src << 9) + loff));
      const uint4* ee = (const uint4*)(lbase + (e << 5));
      edge_math(ee[0], ee[1], qv);
    }
    // overflow beyond EA_CAP2 (statistically never for Poisson(32); kept for safety)
    for (int eg = rpA + lend; eg < rpA + le; eg++) {
      int src = src_perm[eg];
      const uint4* eb = (const uint4*)(ea_perm + (size_t)eg * 8);
      uint4 a0 = eb[0], a1 = eb[1];
      uint2 qv = *(const uint2*)(qvb + (((unsigned)src << 9) + loff));
      edge_math(a0, a1, qv);
    }

    // skip + LayerNorm + GELU (wave owns full row: 2 channels/lane)
    int row = r0 + ri;
    __half2 hv2 = *(const __half2*)(hbuf + (size_t)row * Hh + c0);
    float y0 = __half2float(hv2.x) + agg0, y1 = __half2float(hv2.y) + agg1;
    float s = y0 + y1;
#pragma unroll
    for (int off = 32; off; off >>= 1) s += __shfl_xor(s, off);
    float mu = s * (1.f / 128.f);
    float d0 = y0 - mu, d1 = y1 - mu;
    float vv = d0 * d0 + d1 * d1;
#pragma unroll
    for (int off = 32; off; off >>= 1) vv += __shfl_xor(vv, off);
    float rstd = rsqrtf(vv * (1.f / 128.f) + 1e-5f);
    float2 lg = *(const float2*)(ln_g_l + c0);
    float2 lb = *(const float2*)(ln_b_l + c0);
    float o0 = d0 * rstd * lg.x + lb.x;
    float o1 = d1 * rstd * lg.y + lb.y;
    o0 = 0.5f * o0 * (1.f + erff(o0 * 0.70710678118654752f));
    o1 = 0.5f * o1 * (1.f + erff(o1 * 0.70710678118654752f));
    *(__half2*)(hbuf + (size_t)row * Hh + c0) = __floats2half2_rn(o0, o1);
  }
}

// ---- out_proj: out = h @ out_w  [N,128]@[128,64], h fp16 ----
__global__ __launch_bounds__(64) void out_proj_kernel(const __half* __restrict__ h,
    const float* __restrict__ w, float* __restrict__ out) {
  __shared__ float hs[16][Hh];
  int r0 = blockIdx.x * 16;    // 6250*16 = 100000 exactly
  const uint4* hg = (const uint4*)(h + (size_t)r0 * Hh);
  for (int i = threadIdx.x; i < 256; i += 64) {
    uint4 u = hg[i];
    int r = i >> 4, c = (i & 15) * 8;
    __half2 ha = u2h2(u.x), hb = u2h2(u.y), hc = u2h2(u.z), hd = u2h2(u.w);
    hs[r][c+0] = __half2float(ha.x); hs[r][c+1] = __half2float(ha.y);
    hs[r][c+2] = __half2float(hb.x); hs[r][c+3] = __half2float(hb.y);
    hs[r][c+4] = __half2float(hc.x); hs[r][c+5] = __half2float(hc.y);
    hs[r][c+6] = __half2float(hd.x); hs[r][c+7] = __half2float(hd.y);
  }
  __syncthreads();
  int t = threadIdx.x;
  float acc[16] = {};
  for (int kk = 0; kk < Hh; kk++) {
    float wv = w[kk * NOUT + t];
#pragma unroll
    for (int r = 0; r < 16; r++) acc[r] += hs[r][kk] * wv;
  }
#pragma unroll
  for (int r = 0; r < 16; r++) out[(size_t)(r0 + r) * NOUT + t] = acc[r];
}

extern "C" void kernel_launch(void* const* d_in, const int* in_sizes, int n_in,
                              void* d_out, int out_size, void* d_ws, size_t ws_size,
                              hipStream_t stream) {
  const float* x    = (const float*)d_in[0];
  const int*   ei   = (const int*)d_in[1];
  const float* ea   = (const float*)d_in[2];
  const float* in_w = (const float*)d_in[3];
  const float* in_b = (const float*)d_in[4];
  const float* Wk   = (const float*)d_in[5];
  const float* bk   = (const float*)d_in[6];
  const float* Wq   = (const float*)d_in[7];
  const float* bq   = (const float*)d_in[8];
  const float* Wv   = (const float*)d_in[9];
  const float* bv   = (const float*)d_in[10];
  const float* We   = (const float*)d_in[11];
  const float* be   = (const float*)d_in[12];
  const float* Ws   = (const float*)d_in[13];
  const float* bs   = (const float*)d_in[14];
  const float* ln_g = (const float*)d_in[15];
  const float* ln_b = (const float*)d_in[16];
  const float* out_w = (const float*)d_in[17];
  float* out = (float*)d_out;

  const int* ei_src = ei;
  const int* ei_dst = ei + Ee;

  size_t NH = (size_t)Nn * Hh;
  char* wsp = (char*)d_ws;
  __half* hA = (__half*)wsp;          wsp += NH * 2;
  __half* hB = (__half*)wsp;          wsp += NH * 2;
  __half* kb = (__half*)wsp;          wsp += NH * 2;
  __half* qvj = (__half*)wsp;         wsp += NH * 2 * 2;   // [N,256] pair-interleaved q|v
  __half* WtT = (__half*)wsp;         wsp += (size_t)NL * 4 * Hh * Hh * 2;
  __half* in_wT = (__half*)wsp;       wsp += (size_t)FIN * Hh * 2;
  int* rowptr = (int*)wsp;            wsp += (Nn + 1) * 4;
  int* cursor = (int*)wsp;            wsp += Nn * 4;
  int* bsums  = (int*)wsp;            wsp += 128 * 4;
  int* src_perm = (int*)wsp;          wsp += (size_t)Ee * 4;
  unsigned int* ea_perm = (unsigned int*)wsp; wsp += (size_t)Ee * 32;

  const int NB_SCAN = (Nn + 1023) / 1024;   // 98

  zero_kernel<<<(Nn + 255) / 256, 256, 0, stream>>>(cursor, Nn);
  hist_kernel<<<(Ee + 255) / 256, 256, 0, stream>>>(ei_dst, cursor);
  scan_block_kernel<<<NB_SCAN, 256, 0, stream>>>(cursor, rowptr, bsums);
  scan_sums_kernel<<<1, 128, 0, stream>>>(bsums, NB_SCAN);
  finalize_rowptr_kernel<<<(Nn + 1 + 255) / 256, 256, 0, stream>>>(rowptr, bsums, cursor);
  fill_perm_kernel<<<(Ee + 255) / 256, 256, 0, stream>>>(ei_src, ei_dst, ea, cursor,
                                                         src_perm, ea_perm);
  prep_weights_kernel<<<dim3(4, NL), 256, 0, stream>>>(Wk, Wq, Wv, Ws, WtT);
  prep_inw_kernel<<<(FIN * Hh + 255) / 256, 256, 0, stream>>>(in_w, in_wT);

  in_proj_mfma_kernel<<<Nn / 32, 256, 0, stream>>>(x, in_wT, in_b, hA);

  __half* h  = hA;
  __half* hn = hB;
  for (int l = 0; l < NL; l++) {
    kqvs_mfma_kernel<<<dim3(4, Nn / 32), 256, 0, stream>>>(h,
        WtT + (size_t)l * 4 * Hh * Hh,
        bk + l * Hh, bq + l * Hh, bv + l * Hh, bs + l * Hh,
        kb, qvj, hn);
    edge_csr_kernel<<<Nn / 8, 256, 0, stream>>>(kb, qvj, src_perm, ea_perm,
        rowptr, We + l * EDIMM * Hh, be + l * Hh,
        ln_g + l * Hh, ln_b + l * Hh, hn);
    __half* tmp = h; h = hn; hn = tmp;
  }

  out_proj_kernel<<<Nn / 16, 64, 0, stream>>>(h, out_w, out);
}

// Round 7
// 1111.094 us; speedup vs baseline: 1.3018x; 1.0661x over previous
//
#include <hip/hip_runtime.h>
#include <hip/hip_fp16.h>
#include <cmath>

#define Nn   100000
#define Ee   1600000
#define FIN  256
#define Hh   128
#define EDIMM 16
#define NL   3
#define NOUT 64
#define LOG2E 1.4426950408889634f

typedef _Float16 f16x8 __attribute__((ext_vector_type(8)));
typedef float f32x4 __attribute__((ext_vector_type(4)));

static __device__ __forceinline__ __half2 u2h2(unsigned int u) {
  union { unsigned int u; __half2 h; } c; c.u = u; return c.h;
}
static __device__ __forceinline__ unsigned int h22u(__half2 h) {
  union { unsigned int u; __half2 h; } c; c.h = h; return c.u;
}

// v_pk_fma_f16 with op_sel broadcasting lo/hi half of the packed ea operand:
#define PK_FMA_LO(acc, a, w) \
  asm("v_pk_fma_f16 %0, %1, %2, %0 op_sel:[0,0,0] op_sel_hi:[0,1,1]" \
      : "+v"(acc) : "v"(a), "v"(w))
#define PK_FMA_HI(acc, a, w) \
  asm("v_pk_fma_f16 %0, %1, %2, %0 op_sel:[1,0,0] op_sel_hi:[1,1,1]" \
      : "+v"(acc) : "v"(a), "v"(w))

// ---- prep: in_wT[n][k] = in_w[k][n] as fp16 ----
__global__ __launch_bounds__(256) void prep_inw_kernel(const float* __restrict__ in_w,
    __half* __restrict__ in_wT) {
  int i = blockIdx.x * 256 + threadIdx.x;   // 32768 = FIN*Hh
  if (i < FIN * Hh) {
    int k = i >> 7, n = i & 127;
    in_wT[(size_t)n * FIN + k] = __float2half(in_w[i]);
  }
}

// ---- in_proj via MFMA: h = x @ in_w + in_b, K=256 in two phases over shared LDS ----
__global__ __launch_bounds__(256) void in_proj_mfma_kernel(const float* __restrict__ x,
    const __half* __restrict__ in_wT, const float* __restrict__ b, __half* __restrict__ h) {
  __shared__ __half Wl[128][136];
  __shared__ __half Ht[32][136];
  int r0 = blockIdx.x * 32;      // 3125*32 = 100000 exactly
  int tid = threadIdx.x;
  int wv = tid >> 6, lane = tid & 63;
  int rowHalf = wv & 1, colHalf = wv >> 1;
  int quad = lane >> 4, l16 = lane & 15;

  f32x4 acc[4];
#pragma unroll
  for (int t = 0; t < 4; t++) acc[t] = (f32x4){0.f, 0.f, 0.f, 0.f};

  for (int ph = 0; ph < 2; ph++) {
    for (int i = tid; i < 2048; i += 256) {
      int rw = i >> 4, cw = i & 15;
      *(uint4*)(&Wl[rw][cw * 8]) =
          *(const uint4*)(in_wT + (size_t)rw * FIN + ph * 128 + cw * 8);
    }
    for (int i = tid; i < 1024; i += 256) {
      int r = i >> 5, c4 = i & 31;
      float4 f = *(const float4*)(x + (size_t)(r0 + r) * FIN + ph * 128 + c4 * 4);
      *(uint2*)(&Ht[r][c4 * 4]) =
          make_uint2(h22u(__floats2half2_rn(f.x, f.y)), h22u(__floats2half2_rn(f.z, f.w)));
    }
    __syncthreads();
#pragma unroll
    for (int kstep = 0; kstep < 4; kstep++) {
      f16x8 afrag = *(const f16x8*)(&Ht[rowHalf * 16 + l16][kstep * 32 + quad * 8]);
#pragma unroll
      for (int t = 0; t < 4; t++) {
        int n = colHalf * 64 + t * 16 + l16;
        f16x8 bfrag = *(const f16x8*)(&Wl[n][kstep * 32 + quad * 8]);
        acc[t] = __builtin_amdgcn_mfma_f32_16x16x32_f16(afrag, bfrag, acc[t], 0, 0, 0);
      }
    }
    __syncthreads();
  }

#pragma unroll
  for (int t = 0; t < 4; t++) {
    int col = colHalf * 64 + t * 16 + l16;
    float bval = b[col];
#pragma unroll
    for (int r = 0; r < 4; r++) {
      int row = r0 + rowHalf * 16 + quad * 4 + r;
      h[(size_t)row * Hh + col] = __float2half(acc[t][r] + bval);
    }
  }
}

// ---- prep: WtT[l][mat][n][k] = W_mat[l][k][n] as fp16; gate mats (k,q) pre-scaled by log2e ----
__global__ __launch_bounds__(256) void prep_weights_kernel(const float* __restrict__ Wk,
    const float* __restrict__ Wq, const float* __restrict__ Wv, const float* __restrict__ Ws,
    __half* __restrict__ WtT) {
  int mat = blockIdx.x, l = blockIdx.y;
  const float* W = (mat == 0 ? Wk : mat == 1 ? Wq : mat == 2 ? Wv : Ws) + (size_t)l * Hh * Hh;
  float sc = (mat < 2) ? LOG2E : 1.f;
  __half* out = WtT + ((size_t)(l * 4 + mat)) * Hh * Hh;
  for (int i = threadIdx.x; i < Hh * Hh; i += 256) {
    int k = i >> 7, n = i & 127;
    out[(size_t)n * Hh + k] = __float2half(W[i] * sc);
  }
}

// ---- MFMA kqvs: grid (4, 625); block stages W ONCE, loops 5 row-tiles with
// double-buffered Ht (next tile's h loads issued before the barrier, written after
// the MFMAs). Kills the 400 MB/layer W re-stage of the 1-tile version.
#define KQVS_TPB 5   // tiles per block: 625*5 = 3125 tiles = 100000 rows
__global__ __launch_bounds__(256) void kqvs_mfma_kernel(
    const __half* __restrict__ h, const __half* __restrict__ WtT_l,
    const float* __restrict__ bk, const float* __restrict__ bq,
    const float* __restrict__ bv, const float* __restrict__ bs,
    __half* __restrict__ kb, __half* __restrict__ qvj, __half* __restrict__ hnew) {
  __shared__ __half Wl[128][136];
  __shared__ __half Ht[2][32][136];
  int mat = blockIdx.x;
  int tb = blockIdx.y * KQVS_TPB;
  int tid = threadIdx.x;

  // stage W once (32 KB)
  const uint4* wg = (const uint4*)(WtT_l + (size_t)mat * Hh * Hh);
#pragma unroll
  for (int j = 0; j < 8; j++) {
    int i = tid + 256 * j;
    int rw = i >> 4, cw = i & 15;
    *(uint4*)(&Wl[rw][cw * 8]) = wg[i];
  }
  // stage h tile 0 into Ht[0]
  {
    const uint4* hg = (const uint4*)(h + (size_t)tb * 32 * Hh);
    uint4 a = hg[tid], b4 = hg[tid + 256];
    int rh = tid >> 4, ch = tid & 15;
    *(uint4*)(&Ht[0][rh][ch * 8]) = a;
    int i2 = tid + 256; rh = i2 >> 4; ch = i2 & 15;
    *(uint4*)(&Ht[0][rh][ch * 8]) = b4;
  }

  int wv = tid >> 6, lane = tid & 63;
  int rowHalf = wv & 1, colHalf = wv >> 1;
  int quad = lane >> 4, l16 = lane & 15;

  const float* bp = (mat == 0) ? bk : (mat == 1) ? bq : (mat == 2) ? bv : bs;
  float bscale = (mat < 2) ? LOG2E : 1.f;
  float bval[4];
#pragma unroll
  for (int t = 0; t < 4; t++) bval[t] = bp[colHalf * 64 + t * 16 + l16] * bscale;

  int cur = 0;
#pragma unroll 1
  for (int it = 0; it < KQVS_TPB; it++) {
    // issue next tile's h loads early (consumed after this tile's MFMAs)
    uint4 ha, hb;
    if (it < KQVS_TPB - 1) {
      const uint4* hg = (const uint4*)(h + (size_t)(tb + it + 1) * 32 * Hh);
      ha = hg[tid]; hb = hg[tid + 256];
    }
    __syncthreads();   // Ht[cur] writes (prev iter / prologue) visible

    f32x4 acc[4];
#pragma unroll
    for (int t = 0; t < 4; t++) acc[t] = (f32x4){0.f, 0.f, 0.f, 0.f};
#pragma unroll
    for (int kstep = 0; kstep < 4; kstep++) {
      f16x8 afrag = *(const f16x8*)(&Ht[cur][rowHalf * 16 + l16][kstep * 32 + quad * 8]);
#pragma unroll
      for (int t = 0; t < 4; t++) {
        int n = colHalf * 64 + t * 16 + l16;
        f16x8 bfrag = *(const f16x8*)(&Wl[n][kstep * 32 + quad * 8]);
        acc[t] = __builtin_amdgcn_mfma_f32_16x16x32_f16(afrag, bfrag, acc[t], 0, 0, 0);
      }
    }

    int r0 = (tb + it) * 32;
#pragma unroll
    for (int t = 0; t < 4; t++) {
      int col = colHalf * 64 + t * 16 + l16;
#pragma unroll
      for (int r = 0; r < 4; r++) {
        int row = r0 + rowHalf * 16 + quad * 4 + r;
        __half hv = __float2half(acc[t][r] + bval[t]);
        if (mat == 0)       kb[(size_t)row * Hh + col] = hv;
        else if (mat == 1)  qvj[(size_t)row * 256 + (col >> 1) * 4 + (col & 1)] = hv;
        else if (mat == 2)  qvj[(size_t)row * 256 + (col >> 1) * 4 + 2 + (col & 1)] = hv;
        else                hnew[(size_t)row * Hh + col] = hv;
      }
    }

    if (it < KQVS_TPB - 1) {   // write next tile into the other buffer
      int rh = tid >> 4, ch = tid & 15;
      *(uint4*)(&Ht[cur ^ 1][rh][ch * 8]) = ha;
      int i2 = tid + 256; rh = i2 >> 4; ch = i2 & 15;
      *(uint4*)(&Ht[cur ^ 1][rh][ch * 8]) = hb;
      cur ^= 1;
    }
  }
}

// ---------------- CSR build ----------------
__global__ __launch_bounds__(256) void zero_kernel(int* __restrict__ p, int n) {
  int i = blockIdx.x * 256 + threadIdx.x;
  if (i < n) p[i] = 0;
}

__global__ __launch_bounds__(256) void hist_kernel(const int* __restrict__ ei_dst,
                                                   int* __restrict__ counts) {
  int e = blockIdx.x * 256 + threadIdx.x;
  if (e < Ee) atomicAdd(&counts[ei_dst[e]], 1);
}

__global__ __launch_bounds__(256) void scan_block_kernel(const int* __restrict__ counts,
    int* __restrict__ rowptr, int* __restrict__ bsums) {
  __shared__ int tsums[256];
  int b = blockIdx.x, t = threadIdx.x;
  int base = b * 1024 + t * 4;
  int v[4]; int s = 0;
#pragma unroll
  for (int j = 0; j < 4; j++) {
    int idx = base + j;
    v[j] = (idx < Nn) ? counts[idx] : 0;
    s += v[j];
  }
  tsums[t] = s;
  __syncthreads();
  for (int off = 1; off < 256; off <<= 1) {
    int y = (t >= off) ? tsums[t - off] : 0;
    __syncthreads();
    tsums[t] += y;
    __syncthreads();
  }
  int excl = tsums[t] - s;
#pragma unroll
  for (int j = 0; j < 4; j++) {
    int idx = base + j;
    if (idx < Nn) rowptr[idx] = excl;
    excl += v[j];
  }
  if (t == 255) bsums[b] = tsums[255];
}

__global__ __launch_bounds__(128) void scan_sums_kernel(int* __restrict__ bsums, int nb) {
  __shared__ int sh[128];
  int t = threadIdx.x;
  int v = (t < nb) ? bsums[t] : 0;
  sh[t] = v;
  __syncthreads();
  for (int off = 1; off < 128; off <<= 1) {
    int y = (t >= off) ? sh[t - off] : 0;
    __syncthreads();
    sh[t] += y;
    __syncthreads();
  }
  if (t < nb) bsums[t] = sh[t] - v;
}

__global__ __launch_bounds__(256) void finalize_rowptr_kernel(int* __restrict__ rowptr,
    const int* __restrict__ bsums, int* __restrict__ cursor) {
  int i = blockIdx.x * 256 + threadIdx.x;
  if (i < Nn) {
    int r = rowptr[i] + bsums[i >> 10];
    rowptr[i] = r;
    cursor[i] = r;
  }
  if (i == Nn) rowptr[Nn] = Ee;
}

// permute: src_perm (int), ea_perm = raw packed fp16 (8 uints/edge, 32 B)
__global__ __launch_bounds__(256) void fill_perm_kernel(const int* __restrict__ ei_src,
    const int* __restrict__ ei_dst, const float* __restrict__ ea,
    int* __restrict__ cursor, int* __restrict__ src_perm,
    unsigned int* __restrict__ ea_perm) {
  int e = blockIdx.x * 256 + threadIdx.x;
  if (e < Ee) {
    int d = ei_dst[e];
    int slot = atomicAdd(&cursor[d], 1);
    src_perm[slot] = ei_src[e];
    const float4* s = (const float4*)(ea + (size_t)e * EDIMM);
    float4 f0 = s[0], f1 = s[1], f2 = s[2], f3 = s[3];
    uint4* dp = (uint4*)(ea_perm + (size_t)slot * 8);
    dp[0] = make_uint4(h22u(__floats2half2_rn(f0.x, f0.y)), h22u(__floats2half2_rn(f0.z, f0.w)),
                       h22u(__floats2half2_rn(f1.x, f1.y)), h22u(__floats2half2_rn(f1.z, f1.w)));
    dp[1] = make_uint4(h22u(__floats2half2_rn(f2.x, f2.y)), h22u(__floats2half2_rn(f2.z, f2.w)),
                       h22u(__floats2half2_rn(f3.x, f3.y)), h22u(__floats2half2_rn(f3.z, f3.w)));
  }
}

// ---- CSR edge kernel: one wave per TWO consecutive dst rows (unchanged from R6) ----
#define EA_CAP2 80   // edges staged per wave (2 rows); 10 KiB/block; overflow path below
__global__ __launch_bounds__(256, 6) void edge_csr_kernel(
    const __half* __restrict__ kb, const __half* __restrict__ qvj,
    const int* __restrict__ src_perm, const unsigned int* __restrict__ ea_perm,
    const int* __restrict__ rowptr,
    const float* __restrict__ We_l, const float* __restrict__ be_l,
    const float* __restrict__ ln_g_l, const float* __restrict__ ln_b_l,
    __half* __restrict__ hbuf) {
  __shared__ uint4 lds_ea[4][EA_CAP2 * 2];   // 4 waves x 80 edges x 32 B = 10 KiB
  int wave = threadIdx.x >> 6;
  int lane = threadIdx.x & 63;
  int r0 = (blockIdx.x * 4 + wave) * 2;   // grid 12500*4 waves*2 rows = 100000 exactly
  int c0 = lane * 2;

  unsigned wpk[EDIMM];   // We columns (c0,c0+1) per dim, fp16 pair, pre-scaled by log2e
#pragma unroll
  for (int d = 0; d < EDIMM; d++) {
    float2 wv = *(const float2*)(We_l + d * Hh + c0);
    wpk[d] = h22u(__floats2half2_rn(wv.x * LOG2E, wv.y * LOG2E));
  }
  float2 bef = *(const float2*)(be_l + c0);
  __half2 bev = __floats2half2_rn(bef.x * LOG2E, bef.y * LOG2E);

  int rpA = rowptr[r0], rpB = rowptr[r0 + 1], rpC = rowptr[r0 + 2];

  unsigned kbev0 = h22u(__hadd2(*(const __half2*)(kb + (size_t)r0 * Hh + c0), bev));
  unsigned kbev1 = h22u(__hadd2(*(const __half2*)(kb + (size_t)(r0 + 1) * Hh + c0), bev));

  int nl = rpC - rpA;
  if (nl > EA_CAP2) nl = EA_CAP2;   // edges resident in LDS (local idx < nl)

  // ---- stage both rows' ea (contiguous in CSR order) into LDS ----
  char* lbase = (char*)&lds_ea[wave][0];
  {
    int row_bytes = nl << 5;
    const char* gsrc = (const char*)(ea_perm + (size_t)rpA * 8);
    for (int c = 0; c < row_bytes; c += 1024) {
      int o = c + lane * 16;
      if (o < row_bytes) {
        __builtin_amdgcn_global_load_lds(
            (__attribute__((address_space(1))) void*)(gsrc + o),
            (__attribute__((address_space(3))) void*)(lbase + c),
            16, 0, 0);
      }
    }
  }

  const char* qvb = (const char*)qvj;
  unsigned loff = (unsigned)(lane << 3);
  const int* spb = src_perm + rpA;   // local-index base

#pragma unroll
  for (int ri = 0; ri < 2; ri++) {
    unsigned kb_u = ri ? kbev1 : kbev0;
    float agg0 = 0.f, agg1 = 0.f;
    int ls = (ri ? rpB : rpA) - rpA;
    int le = (ri ? rpC : rpB) - rpA;
    int lend = le < nl ? le : nl;
    if (lend < ls) lend = ls;

    auto edge_math = [&](uint4 eA, uint4 eB, uint2 qv) {
      unsigned acc = kb_u;
      PK_FMA_LO(acc, eA.x, wpk[0]);  PK_FMA_HI(acc, eA.x, wpk[1]);
      PK_FMA_LO(acc, eA.y, wpk[2]);  PK_FMA_HI(acc, eA.y, wpk[3]);
      PK_FMA_LO(acc, eA.z, wpk[4]);  PK_FMA_HI(acc, eA.z, wpk[5]);
      PK_FMA_LO(acc, eA.w, wpk[6]);  PK_FMA_HI(acc, eA.w, wpk[7]);
      PK_FMA_LO(acc, eB.x, wpk[8]);  PK_FMA_HI(acc, eB.x, wpk[9]);
      PK_FMA_LO(acc, eB.y, wpk[10]); PK_FMA_HI(acc, eB.y, wpk[11]);
      PK_FMA_LO(acc, eB.z, wpk[12]); PK_FMA_HI(acc, eB.z, wpk[13]);
      PK_FMA_LO(acc, eB.w, wpk[14]); PK_FMA_HI(acc, eB.w, wpk[15]);
      __half2 pre = __hadd2(u2h2(acc), u2h2(qv.x));
      float p0 = __half2float(__low2half(pre));
      float p1 = __half2float(__high2half(pre));
      float ex0, ex1;
      asm("v_exp_f32 %0, -%1" : "=v"(ex0) : "v"(p0));   // exp2(-pre); pre is log2e-scaled
      asm("v_exp_f32 %0, -%1" : "=v"(ex1) : "v"(p1));
      float g0 = __builtin_amdgcn_rcpf(1.f + ex0);
      float g1 = __builtin_amdgcn_rcpf(1.f + ex1);
      __half2 vh = u2h2(qv.y);
      agg0 += g0 * __half2float(__low2half(vh));
      agg1 += g1 * __half2float(__high2half(vh));
    };

    int e = ls;
    int nfull = (lend - e) & ~3;
    int nfe = e + nfull;
    uint2 qA0, qA1, qA2, qA3;
    if (nfull) {
      int4 s4 = *(const int4*)(spb + e);
      qA0 = *(const uint2*)(qvb + (((unsigned)s4.x << 9) + loff));
      qA1 = *(const uint2*)(qvb + (((unsigned)s4.y << 9) + loff));
      qA2 = *(const uint2*)(qvb + (((unsigned)s4.z << 9) + loff));
      qA3 = *(const uint2*)(qvb + (((unsigned)s4.w << 9) + loff));
    }
    // ri=0: drains ea staging + first gathers. ri=1: drains only its fresh gathers.
    asm volatile("s_waitcnt vmcnt(0)" ::: "memory");

    for (; e + 8 <= nfe; e += 4) {
      int4 s4n = *(const int4*)(spb + e + 4);
      uint2 qB0 = *(const uint2*)(qvb + (((unsigned)s4n.x << 9) + loff));
      uint2 qB1 = *(const uint2*)(qvb + (((unsigned)s4n.y << 9) + loff));
      uint2 qB2 = *(const uint2*)(qvb + (((unsigned)s4n.z << 9) + loff));
      uint2 qB3 = *(const uint2*)(qvb + (((unsigned)s4n.w << 9) + loff));
      const uint4* ee = (const uint4*)(lbase + (e << 5));
      edge_math(ee[0], ee[1], qA0);
      edge_math(ee[2], ee[3], qA1);
      edge_math(ee[4], ee[5], qA2);
      edge_math(ee[6], ee[7], qA3);
      qA0 = qB0; qA1 = qB1; qA2 = qB2; qA3 = qB3;
    }
    if (nfull) {
      const uint4* ee = (const uint4*)(lbase + (e << 5));
      edge_math(ee[0], ee[1], qA0);
      edge_math(ee[2], ee[3], qA1);
      edge_math(ee[4], ee[5], qA2);
      edge_math(ee[6], ee[7], qA3);
      e += 4;
    }
    for (; e < lend; e++) {
      int src = spb[e];
      uint2 qv = *(const uint2*)(qvb + (((unsigned)src << 9) + loff));
      const uint4* ee = (const uint4*)(lbase + (e << 5));
      edge_math(ee[0], ee[1], qv);
    }
    // overflow beyond EA_CAP2 (statistically never for Poisson(32); kept for safety)
    for (int eg = rpA + lend; eg < rpA + le; eg++) {
      int src = src_perm[eg];
      const uint4* eb = (const uint4*)(ea_perm + (size_t)eg * 8);
      uint4 a0 = eb[0], a1 = eb[1];
      uint2 qv = *(const uint2*)(qvb + (((unsigned)src << 9) + loff));
      edge_math(a0, a1, qv);
    }

    // skip + LayerNorm + GELU (wave owns full row: 2 channels/lane)
    int row = r0 + ri;
    __half2 hv2 = *(const __half2*)(hbuf + (size_t)row * Hh + c0);
    float y0 = __half2float(hv2.x) + agg0, y1 = __half2float(hv2.y) + agg1;
    float s = y0 + y1;
#pragma unroll
    for (int off = 32; off; off >>= 1) s += __shfl_xor(s, off);
    float mu = s * (1.f / 128.f);
    float d0 = y0 - mu, d1 = y1 - mu;
    float vv = d0 * d0 + d1 * d1;
#pragma unroll
    for (int off = 32; off; off >>= 1) vv += __shfl_xor(vv, off);
    float rstd = rsqrtf(vv * (1.f / 128.f) + 1e-5f);
    float2 lg = *(const float2*)(ln_g_l + c0);
    float2 lb = *(const float2*)(ln_b_l + c0);
    float o0 = d0 * rstd * lg.x + lb.x;
    float o1 = d1 * rstd * lg.y + lb.y;
    o0 = 0.5f * o0 * (1.f + erff(o0 * 0.70710678118654752f));
    o1 = 0.5f * o1 * (1.f + erff(o1 * 0.70710678118654752f));
    *(__half2*)(hbuf + (size_t)row * Hh + c0) = __floats2half2_rn(o0, o1);
  }
}

// ---- out_proj: out = h @ out_w  [N,128]@[128,64], h fp16 ----
__global__ __launch_bounds__(64) void out_proj_kernel(const __half* __restrict__ h,
    const float* __restrict__ w, float* __restrict__ out) {
  __shared__ float hs[16][Hh];
  int r0 = blockIdx.x * 16;    // 6250*16 = 100000 exactly
  const uint4* hg = (const uint4*)(h + (size_t)r0 * Hh);
  for (int i = threadIdx.x; i < 256; i += 64) {
    uint4 u = hg[i];
    int r = i >> 4, c = (i & 15) * 8;
    __half2 ha = u2h2(u.x), hb = u2h2(u.y), hc = u2h2(u.z), hd = u2h2(u.w);
    hs[r][c+0] = __half2float(ha.x); hs[r][c+1] = __half2float(ha.y);
    hs[r][c+2] = __half2float(hb.x); hs[r][c+3] = __half2float(hb.y);
    hs[r][c+4] = __half2float(hc.x); hs[r][c+5] = __half2float(hc.y);
    hs[r][c+6] = __half2float(hd.x); hs[r][c+7] = __half2float(hd.y);
  }
  __syncthreads();
  int t = threadIdx.x;
  float acc[16] = {};
  for (int kk = 0; kk < Hh; kk++) {
    float wv = w[kk * NOUT + t];
#pragma unroll
    for (int r = 0; r < 16; r++) acc[r] += hs[r][kk] * wv;
  }
#pragma unroll
  for (int r = 0; r < 16; r++) out[(size_t)(r0 + r) * NOUT + t] = acc[r];
}

extern "C" void kernel_launch(void* const* d_in, const int* in_sizes, int n_in,
                              void* d_out, int out_size, void* d_ws, size_t ws_size,
                              hipStream_t stream) {
  const float* x    = (const float*)d_in[0];
  const int*   ei   = (const int*)d_in[1];
  const float* ea   = (const float*)d_in[2];
  const float* in_w = (const float*)d_in[3];
  const float* in_b = (const float*)d_in[4];
  const float* Wk   = (const float*)d_in[5];
  const float* bk   = (const float*)d_in[6];
  const float* Wq   = (const float*)d_in[7];
  const float* bq   = (const float*)d_in[8];
  const float* Wv   = (const float*)d_in[9];
  const float* bv   = (const float*)d_in[10];
  const float* We   = (const float*)d_in[11];
  const float* be   = (const float*)d_in[12];
  const float* Ws   = (const float*)d_in[13];
  const float* bs   = (const float*)d_in[14];
  const float* ln_g = (const float*)d_in[15];
  const float* ln_b = (const float*)d_in[16];
  const float* out_w = (const float*)d_in[17];
  float* out = (float*)d_out;

  const int* ei_src = ei;
  const int* ei_dst = ei + Ee;

  size_t NH = (size_t)Nn * Hh;
  char* wsp = (char*)d_ws;
  __half* hA = (__half*)wsp;          wsp += NH * 2;
  __half* hB = (__half*)wsp;          wsp += NH * 2;
  __half* kb = (__half*)wsp;          wsp += NH * 2;
  __half* qvj = (__half*)wsp;         wsp += NH * 2 * 2;   // [N,256] pair-interleaved q|v
  __half* WtT = (__half*)wsp;         wsp += (size_t)NL * 4 * Hh * Hh * 2;
  __half* in_wT = (__half*)wsp;       wsp += (size_t)FIN * Hh * 2;
  int* rowptr = (int*)wsp;            wsp += (Nn + 1) * 4;
  int* cursor = (int*)wsp;            wsp += Nn * 4;
  int* bsums  = (int*)wsp;            wsp += 128 * 4;
  int* src_perm = (int*)wsp;          wsp += (size_t)Ee * 4;
  unsigned int* ea_perm = (unsigned int*)wsp; wsp += (size_t)Ee * 32;

  const int NB_SCAN = (Nn + 1023) / 1024;   // 98

  zero_kernel<<<(Nn + 255) / 256, 256, 0, stream>>>(cursor, Nn);
  hist_kernel<<<(Ee + 255) / 256, 256, 0, stream>>>(ei_dst, cursor);
  scan_block_kernel<<<NB_SCAN, 256, 0, stream>>>(cursor, rowptr, bsums);
  scan_sums_kernel<<<1, 128, 0, stream>>>(bsums, NB_SCAN);
  finalize_rowptr_kernel<<<(Nn + 1 + 255) / 256, 256, 0, stream>>>(rowptr, bsums, cursor);
  fill_perm_kernel<<<(Ee + 255) / 256, 256, 0, stream>>>(ei_src, ei_dst, ea, cursor,
                                                         src_perm, ea_perm);
  prep_weights_kernel<<<dim3(4, NL), 256, 0, stream>>>(Wk, Wq, Wv, Ws, WtT);
  prep_inw_kernel<<<(FIN * Hh + 255) / 256, 256, 0, stream>>>(in_w, in_wT);

  in_proj_mfma_kernel<<<Nn / 32, 256, 0, stream>>>(x, in_wT, in_b, hA);

  __half* h  = hA;
  __half* hn = hB;
  for (int l = 0; l < NL; l++) {
    kqvs_mfma_kernel<<<dim3(4, 625), 256, 0, stream>>>(h,
        WtT + (size_t)l * 4 * Hh * Hh,
        bk + l * Hh, bq + l * Hh, bv + l * Hh, bs + l * Hh,
        kb, qvj, hn);
    edge_csr_kernel<<<Nn / 8, 256, 0, stream>>>(kb, qvj, src_perm, ea_perm,
        rowptr, We + l * EDIMM * Hh, be + l * Hh,
        ln_g + l * Hh, ln_b + l * Hh, hn);
    __half* tmp = h; h = hn; hn = tmp;
  }

  out_proj_kernel<<<Nn / 16, 64, 0, stream>>>(h, out_w, out);
}